// Round 1
// baseline (224.473 us; speedup 1.0000x reference)
//
#include <hip/hip_runtime.h>

// EMA along T for pos_seq (B, T=8192, C=51) fp32.
// y[b,0,c] = x[b,0,c];  y[b,t,c] = 0.25*x[b,t,c] + 0.75*y[b,t-1,c]
//
// Strategy: chunk T into L=128 blocks per thread; recurrence forgets at
// 0.75^t, so seeding each chunk with a H=48-step halo warm-up (carry
// initialized to x[t0-H]) gives absolute error <= 0.75^48 * O(10) ~ 1e-5,
// far below the 7.4e-2 tolerance. Chunk 0 is exact.
// Thread mapping: gid -> (b, chunk, c) with c fastest => wave lanes read
// contiguous 204B rows; sequential t walks memory contiguously.

#define EMA_ALPHA 0.25f
#define EMA_BETA  0.75f
#define T_DIM 8192
#define C_DIM 51
#define CHUNK_L 128
#define HALO_H  48
#define NCHUNK (T_DIM / CHUNK_L)   // 64

__global__ __launch_bounds__(256) void ema_kernel(const float* __restrict__ x,
                                                  float* __restrict__ y,
                                                  int total_threads) {
    int gid = blockIdx.x * blockDim.x + threadIdx.x;
    if (gid >= total_threads) return;

    int c = gid % C_DIM;
    int rest = gid / C_DIM;
    int chunk = rest % NCHUNK;
    int b = rest / NCHUNK;

    const size_t seq_base = (size_t)b * T_DIM * C_DIM + c;
    const float* __restrict__ xb = x + seq_base;
    float* __restrict__ yb = y + seq_base;

    const int t0 = chunk * CHUNK_L;
    float acc;
    int tstart;

    if (chunk == 0) {
        // exact start
        acc = xb[0];
        yb[0] = acc;
        tstart = 1;
    } else {
        // halo warm-up: seed with x[t0-H], run H-1 un-stored steps
        int th = t0 - HALO_H;
        acc = xb[(size_t)th * C_DIM];
#pragma unroll
        for (int i = 1; i < HALO_H; ++i) {
            float xv = xb[(size_t)(th + i) * C_DIM];
            acc = fmaf(EMA_ALPHA, xv, EMA_BETA * acc);
        }
        tstart = t0;
    }

    const int tend = t0 + CHUNK_L;
#pragma unroll 8
    for (int t = tstart; t < tend; ++t) {
        float xv = xb[(size_t)t * C_DIM];
        acc = fmaf(EMA_ALPHA, xv, EMA_BETA * acc);
        yb[(size_t)t * C_DIM] = acc;
    }
}

extern "C" void kernel_launch(void* const* d_in, const int* in_sizes, int n_in,
                              void* d_out, int out_size, void* d_ws, size_t ws_size,
                              hipStream_t stream) {
    const float* x = (const float*)d_in[0];
    float* y = (float*)d_out;

    int B = in_sizes[0] / (T_DIM * C_DIM);   // 64
    int total = B * NCHUNK * C_DIM;          // 208896
    int block = 256;
    int grid = (total + block - 1) / block;  // 816

    ema_kernel<<<grid, block, 0, stream>>>(x, y, total);
}